// Round 10
// baseline (698.832 us; speedup 1.0000x reference)
//
#include <hip/hip_runtime.h>
#include <cstdint>
#include <cstddef>

#define B_   8
#define N_   16384
#define MA_  256
#define MB_  64
#define KI_  3
#define KAB_ 16

// output region offsets (floats)
#define OFF_PCC 0            // pc_centers      (8,3,16384)  393216
#define OFF_CM  393216       // cluster_mean    (8,3,256)    6144
#define OFF_MKI 399360       // min_k_idx       (8,16384,3)  393216 (as float)
#define OFF_F1  792576       // f1              (8,32,16384) 4194304
#define OFF_F2  4986880      // f2              (8,64,16384) 8388608
#define OFF_NAF 13375488     // node_a_features (8,64,256)   131072
#define OFF_NBF 13506560     // node_b_features (8,256,64)   131072
#define OFF_GF  13637632     // global_feature  (8,1024,1)   8192

// ---------------------------------------------------------------------------
// K1: per-point top-3 nearest node_a + fused segment count/sum atomics
// ---------------------------------------------------------------------------
__global__ __launch_bounds__(256) void k_top3(
    const float* __restrict__ pc, const float* __restrict__ node_a,
    float* __restrict__ out_mki, int* __restrict__ minidx,
    float* __restrict__ counts, float* __restrict__ sums)
{
#pragma clang fp contract(off)
    __shared__ float nax[MA_], nay[MA_], naz[MA_];
    int b = blockIdx.y;
    const float* na = node_a + (size_t)b * 3 * MA_;
    for (int t = threadIdx.x; t < MA_; t += 256) {
        nax[t] = na[t]; nay[t] = na[MA_ + t]; naz[t] = na[2 * MA_ + t];
    }
    __syncthreads();
    int n = blockIdx.x * 256 + threadIdx.x;
    const float* pcb = pc + (size_t)b * 3 * N_;
    float px = pcb[n], py = pcb[N_ + n], pz = pcb[2 * N_ + n];
    float d0 = 3.4e38f, d1 = 3.4e38f, d2 = 3.4e38f;
    int   i0 = 0, i1 = 0, i2 = 0;
    for (int m = 0; m < MA_; ++m) {
        float dx = px - nax[m];
        float dy = py - nay[m];
        float dz = pz - naz[m];
        float s = dx * dx;
        s = s + dy * dy;
        s = s + dz * dz;
        float d = sqrtf(s);
        // strict < keeps lower index first on ties (matches jax.lax.top_k)
        if (d < d2) {
            if (d < d1) {
                if (d < d0) { d2 = d1; i2 = i1; d1 = d0; i1 = i0; d0 = d; i0 = m; }
                else        { d2 = d1; i2 = i1; d1 = d;  i1 = m; }
            } else          { d2 = d;  i2 = m; }
        }
    }
    size_t base = ((size_t)b * N_ + n) * 3;
    out_mki[base + 0] = (float)i0;
    out_mki[base + 1] = (float)i1;
    out_mki[base + 2] = (float)i2;
    minidx[b * N_ + n] = i0;
    atomicAdd(&counts[b * MA_ + i0], 1.0f);
    atomicAdd(&sums[(b * 3 + 0) * MA_ + i0], px);
    atomicAdd(&sums[(b * 3 + 1) * MA_ + i0], py);
    atomicAdd(&sums[(b * 3 + 2) * MA_ + i0], pz);
}

// ---------------------------------------------------------------------------
// K2: cluster_mean = sums / (counts + 1e-5)
// ---------------------------------------------------------------------------
__global__ void k_mean(const float* __restrict__ counts, const float* __restrict__ sums,
                       float* __restrict__ out_cm)
{
    int tid = blockIdx.x * 256 + threadIdx.x;     // 2048
    int b = tid >> 8, m = tid & 255;
    float den = counts[tid] + 1e-5f;
    #pragma unroll
    for (int c = 0; c < 3; ++c)
        out_cm[(b * 3 + c) * MA_ + m] = sums[(b * 3 + c) * MA_ + m] / den;
}

// ---------------------------------------------------------------------------
// K3: per-point fp1 MLP (8->32->32->32), writes pc_centers & f1 (no atomics)
// ---------------------------------------------------------------------------
__global__ __launch_bounds__(256) void k_fp1(
    const float* __restrict__ pc, const float* __restrict__ inten,
    const float* __restrict__ sn, const float* __restrict__ label,
    const int* __restrict__ minidx, const float* __restrict__ cm,
    const float* __restrict__ w0, const float* __restrict__ b0,
    const float* __restrict__ w1, const float* __restrict__ b1,
    const float* __restrict__ w2, const float* __restrict__ b2,
    float* __restrict__ out_pcc, float* __restrict__ f1out)
{
    __shared__ float w0s[32 * 8], w1s[32 * 32], w2s[32 * 32];
    __shared__ float b0s[32], b1s[32], b2s[32];
    for (int t = threadIdx.x; t < 256; t += 256) w0s[t] = w0[t];
    for (int t = threadIdx.x; t < 1024; t += 256) { w1s[t] = w1[t]; w2s[t] = w2[t]; }
    if (threadIdx.x < 32) {
        b0s[threadIdx.x] = b0[threadIdx.x];
        b1s[threadIdx.x] = b1[threadIdx.x];
        b2s[threadIdx.x] = b2[threadIdx.x];
    }
    __syncthreads();
    int b = blockIdx.y;
    int n = blockIdx.x * 256 + threadIdx.x;
    int mi = minidx[b * N_ + n];
    float cx = cm[(b * 3 + 0) * MA_ + mi];
    float cy = cm[(b * 3 + 1) * MA_ + mi];
    float cz = cm[(b * 3 + 2) * MA_ + mi];
    const float* pcb = pc + (size_t)b * 3 * N_;
    const float* snb = sn + (size_t)b * 3 * N_;
    float x[8];
    x[0] = pcb[n] - cx; x[1] = pcb[N_ + n] - cy; x[2] = pcb[2 * N_ + n] - cz;
    x[3] = inten[(size_t)b * N_ + n];
    x[4] = snb[n]; x[5] = snb[N_ + n]; x[6] = snb[2 * N_ + n];
    x[7] = label[(size_t)b * N_ + n];
    out_pcc[(size_t)(b * 3 + 0) * N_ + n] = cx;
    out_pcc[(size_t)(b * 3 + 1) * N_ + n] = cy;
    out_pcc[(size_t)(b * 3 + 2) * N_ + n] = cz;

    float h1[32];
    #pragma unroll
    for (int o = 0; o < 32; ++o) {
        float a = b0s[o];
        #pragma unroll
        for (int i = 0; i < 8; ++i) a = fmaf(w0s[o * 8 + i], x[i], a);
        h1[o] = a > 0.f ? a : 0.f;
    }
    float h2[32];
    #pragma unroll
    for (int o = 0; o < 32; ++o) {
        float a = b1s[o];
        #pragma unroll
        for (int i = 0; i < 32; ++i) a = fmaf(w1s[o * 32 + i], h1[i], a);
        h2[o] = a > 0.f ? a : 0.f;
    }
    #pragma unroll
    for (int o = 0; o < 32; ++o) {
        float a = b2s[o];
        #pragma unroll
        for (int i = 0; i < 32; ++i) a = fmaf(w2s[o * 32 + i], h2[i], a);
        a = a > 0.f ? a : 0.f;
        f1out[(size_t)(b * 32 + o) * N_ + n] = a;
    }
}

// ---------------------------------------------------------------------------
// K3b: segment-max via LDS table. One block per (b, feature).
// values are post-ReLU (>=0) so float-as-int atomicMax is order-preserving;
// init 0 matches where(nonempty, seg_max, 0).
// ---------------------------------------------------------------------------
__global__ __launch_bounds__(256) void k_segmax(
    const float* __restrict__ f, const int* __restrict__ minidx,
    float* __restrict__ outt, int F)
{
    __shared__ int table[MA_];
    int blk = blockIdx.x;            // b*F + o
    int b = blk / F;
    table[threadIdx.x] = 0;
    __syncthreads();
    const float* frow = f + (size_t)blk * N_;
    const int*   mrow = minidx + (size_t)b * N_;
    #pragma unroll 4
    for (int it = 0; it < N_ / 256; ++it) {
        int n = it * 256 + threadIdx.x;
        float v = frow[n];
        int  mi = mrow[n];
        atomicMax(&table[mi], __float_as_int(v));
    }
    __syncthreads();
    outt[(size_t)blk * MA_ + threadIdx.x] = __int_as_float(table[threadIdx.x]);
}

// ---------------------------------------------------------------------------
// K4: per-point fp2 MLP (64->64->64), writes f2 (no atomics)
// ---------------------------------------------------------------------------
__global__ __launch_bounds__(256) void k_fp2(
    const float* __restrict__ f1, const float* __restrict__ m1,
    const int* __restrict__ minidx,
    const float* __restrict__ w0, const float* __restrict__ b0,
    const float* __restrict__ w1, const float* __restrict__ b1,
    float* __restrict__ f2out)
{
    __shared__ float w0t[64 * 65];   // transposed+padded: w0t[i*65+o] (pad kills staging bank conflicts)
    __shared__ float w1s[64 * 64];   // row-major:  w1s[o*64+i]
    __shared__ float b0s[64], b1s[64];
    for (int t = threadIdx.x; t < 4096; t += 256) {
        w0t[(t & 63) * 65 + (t >> 6)] = w0[t];
        w1s[t] = w1[t];
    }
    if (threadIdx.x < 64) {
        b0s[threadIdx.x] = b0[threadIdx.x];
        b1s[threadIdx.x] = b1[threadIdx.x];
    }
    __syncthreads();
    int b = blockIdx.y;
    int n = blockIdx.x * 256 + threadIdx.x;
    int mi = minidx[b * N_ + n];

    float h[64];
    #pragma unroll
    for (int o = 0; o < 64; ++o) h[o] = b0s[o];
    for (int i = 0; i < 32; ++i) {
        float xi = f1[(size_t)(b * 32 + i) * N_ + n];
        #pragma unroll
        for (int o = 0; o < 64; ++o) h[o] = fmaf(w0t[i * 65 + o], xi, h[o]);
    }
    for (int i = 0; i < 32; ++i) {
        float xi = m1[(b * 32 + i) * MA_ + mi];
        #pragma unroll
        for (int o = 0; o < 64; ++o) h[o] = fmaf(w0t[(32 + i) * 65 + o], xi, h[o]);
    }
    #pragma unroll
    for (int o = 0; o < 64; ++o) h[o] = h[o] > 0.f ? h[o] : 0.f;

    for (int o2 = 0; o2 < 64; ++o2) {
        float acc = b1s[o2];
        #pragma unroll
        for (int i = 0; i < 64; ++i) acc = fmaf(w1s[o2 * 64 + i], h[i], acc);
        acc = acc > 0.f ? acc : 0.f;
        f2out[(size_t)(b * 64 + o2) * N_ + n] = acc;
    }
}

// ---------------------------------------------------------------------------
// K5: per node_b: top-16 nearest cluster means
// ---------------------------------------------------------------------------
__global__ void k_knn16(const float* __restrict__ cm, const float* __restrict__ nb,
                        int* __restrict__ knnidx)
{
#pragma clang fp contract(off)
    __shared__ float dist[MA_];
    int blk = blockIdx.x;            // b*64+mb
    int b = blk >> 6, mb = blk & 63;
    float nbx = nb[(b * 3 + 0) * MB_ + mb];
    float nby = nb[(b * 3 + 1) * MB_ + mb];
    float nbz = nb[(b * 3 + 2) * MB_ + mb];
    for (int m = threadIdx.x; m < MA_; m += 64) {
        float dx = nbx - cm[(b * 3 + 0) * MA_ + m];
        float dy = nby - cm[(b * 3 + 1) * MA_ + m];
        float dz = nbz - cm[(b * 3 + 2) * MA_ + m];
        float s = dx * dx;
        s = s + dy * dy;
        s = s + dz * dz;
        dist[m] = sqrtf(s);
    }
    __syncthreads();
    if (threadIdx.x == 0) {
        for (int k = 0; k < KAB_; ++k) {
            float best = 3.4e38f; int bi = 0;
            for (int m = 0; m < MA_; ++m) {
                float d = dist[m];
                if (d < best) { best = d; bi = m; }   // strict <: lower index wins ties
            }
            knnidx[blk * KAB_ + k] = bi;
            dist[bi] = 3.4e38f;
        }
    }
}

// ---------------------------------------------------------------------------
// K6: build knn1 input matrix X (67 x 8192)
// ---------------------------------------------------------------------------
__global__ void k_buildx(const int* __restrict__ knnidx, const float* __restrict__ cm,
                         const float* __restrict__ nb, const float* __restrict__ naf,
                         float* __restrict__ Xk)
{
    int col = blockIdx.x * 256 + threadIdx.x;   // 8192
    int b = col >> 10;
    int mb = (col >> 4) & 63;
    int idx = knnidx[col];
    #pragma unroll
    for (int c = 0; c < 3; ++c)
        Xk[(size_t)c * 8192 + col] = cm[(b * 3 + c) * MA_ + idx] - nb[(b * 3 + c) * MB_ + mb];
    for (int f = 0; f < 64; ++f)
        Xk[(size_t)(3 + f) * 8192 + col] = naf[(b * 64 + f) * MA_ + idx];
}

// ---------------------------------------------------------------------------
// Tiled f32 GEMM + bias + optional relu + optional per-16-col-group add:
//   Y(O,C) = act( W(O,:)[:,0:I] @ X(I,C) + bias + gadd[o, c>>4] )
// W row stride = lda. 64x64 tile, BK=16, 256 threads, 4x4 per thread.
// Ws padded to 68 floats/row: staging-write bank = (16(t&3)+4j+(t>>2))%32
// covers all 32 banks 2-way (free) instead of 4-way on bank=(t>>2).
// ---------------------------------------------------------------------------
__global__ __launch_bounds__(256) void gemm_relu(
    const float* __restrict__ W, const float* __restrict__ bias,
    const float* __restrict__ X, float* __restrict__ Y,
    int O, int I, int lda, int C,
    const float* __restrict__ gadd, int do_relu)
{
    __shared__ float Ws[16][68];
    __shared__ float Xs[16][64];
    int t  = threadIdx.x;
    int tx = t & 15, ty = t >> 4;
    int obase = blockIdx.y * 64;
    int cbase = blockIdx.x * 64;
    float acc[4][4] = {};
    for (int k0 = 0; k0 < I; k0 += 16) {
        {   // load W tile (transposed into Ws[k][m])
            int m = t >> 2, kq = (t & 3) * 4;
            const float* wrow = W + (size_t)(obase + m) * lda + k0 + kq;
            #pragma unroll
            for (int j = 0; j < 4; ++j) {
                int kk = kq + j;
                Ws[kk][m] = (k0 + kk < I) ? wrow[j] : 0.f;
            }
            // load X tile (lane byte addr = 16*t: contiguous, conflict-free)
            int kx = t >> 4, nq = (t & 15) * 4;
            const float* xrow = X + (size_t)(k0 + kx) * C + cbase + nq;
            bool kok = (k0 + kx) < I;
            #pragma unroll
            for (int j = 0; j < 4; ++j)
                Xs[kx][nq + j] = kok ? xrow[j] : 0.f;
        }
        __syncthreads();
        #pragma unroll
        for (int kk = 0; kk < 16; ++kk) {
            float4 av = *(const float4*)&Ws[kk][ty * 4];
            float4 bv = *(const float4*)&Xs[kk][tx * 4];
            float am[4] = {av.x, av.y, av.z, av.w};
            float bn[4] = {bv.x, bv.y, bv.z, bv.w};
            #pragma unroll
            for (int i = 0; i < 4; ++i)
                #pragma unroll
                for (int j = 0; j < 4; ++j)
                    acc[i][j] = fmaf(am[i], bn[j], acc[i][j]);
        }
        __syncthreads();
    }
    #pragma unroll
    for (int i = 0; i < 4; ++i) {
        int o = obase + ty * 4 + i;
        float bb = bias ? bias[o] : 0.f;
        #pragma unroll
        for (int j = 0; j < 4; ++j) {
            int c = cbase + tx * 4 + j;
            float v = acc[i][j] + bb;
            if (gadd) v += gadd[(size_t)o * 512 + (c >> 4)];
            if (do_relu) v = v > 0.f ? v : 0.f;
            Y[(size_t)o * C + c] = v;
        }
    }
}

// ---------------------------------------------------------------------------
// K7: pooled(256,512) = max over k of Yk2
// ---------------------------------------------------------------------------
__global__ void k_pool(const float* __restrict__ Yk2, float* __restrict__ pooled)
{
    int tid = blockIdx.x * 256 + threadIdx.x;  // 131072
    int r = tid >> 9, g = tid & 511;
    const float* p = Yk2 + (size_t)r * 8192 + g * 16;
    float m = p[0];
    #pragma unroll
    for (int k = 1; k < 16; ++k) m = fmaxf(m, p[k]);
    pooled[r * 512 + g] = m;
}

// ---------------------------------------------------------------------------
// K9: node_b_features = max over k of Z2
// ---------------------------------------------------------------------------
__global__ void k_maxk(const float* __restrict__ Z2, float* __restrict__ nbf)
{
    int tid = blockIdx.x * 256 + threadIdx.x;  // 131072 = (b*256+o)*64+mb
    int mb = tid & 63;
    int o  = (tid >> 6) & 255;
    int b  = tid >> 14;
    const float* p = Z2 + (size_t)o * 8192 + (size_t)((b * 64 + mb) << 4);
    float m = p[0];
    #pragma unroll
    for (int k = 1; k < 16; ++k) m = fmaxf(m, p[k]);
    nbf[tid] = m;
}

// ---------------------------------------------------------------------------
// K10: build fin input (259 x 512)
// ---------------------------------------------------------------------------
__global__ void k_finx(const float* __restrict__ nb, const float* __restrict__ nbf,
                       float* __restrict__ FinX)
{
    int tid = blockIdx.x * 256 + threadIdx.x;  // 132608 = r*512+col
    if (tid >= 259 * 512) return;
    int col = tid & 511, r = tid >> 9;
    int b = col >> 6, mb = col & 63;
    float v = (r < 3) ? nb[(b * 3 + r) * MB_ + mb]
                      : nbf[(b * 256 + (r - 3)) * MB_ + mb];
    FinX[tid] = v;
}

// ---------------------------------------------------------------------------
// K11: global max over the 64 node_b columns
// ---------------------------------------------------------------------------
__global__ void k_gmax(const float* __restrict__ F2, float* __restrict__ gf)
{
    int tid = blockIdx.x * 256 + threadIdx.x;  // 8192 = b*1024+o
    int b = tid >> 10, o = tid & 1023;
    const float* p = F2 + (size_t)o * 512 + b * 64;
    float m = p[0];
    #pragma unroll
    for (int k = 1; k < 64; ++k) m = fmaxf(m, p[k]);
    gf[tid] = m;
}

// ---------------------------------------------------------------------------
extern "C" void kernel_launch(void* const* d_in, const int* in_sizes, int n_in,
                              void* d_out, int out_size, void* d_ws, size_t ws_size,
                              hipStream_t stream)
{
    (void)in_sizes; (void)n_in; (void)out_size; (void)ws_size;
    const float* pc      = (const float*)d_in[0];
    const float* inten   = (const float*)d_in[1];
    const float* sn      = (const float*)d_in[2];
    const float* label   = (const float*)d_in[3];
    const float* node_a  = (const float*)d_in[4];
    const float* node_b  = (const float*)d_in[5];
    const float* fp1_w0  = (const float*)d_in[6];
    const float* fp1_b0  = (const float*)d_in[7];
    const float* fp1_w1  = (const float*)d_in[8];
    const float* fp1_b1  = (const float*)d_in[9];
    const float* fp1_w2  = (const float*)d_in[10];
    const float* fp1_b2  = (const float*)d_in[11];
    const float* fp2_w0  = (const float*)d_in[12];
    const float* fp2_b0  = (const float*)d_in[13];
    const float* fp2_w1  = (const float*)d_in[14];
    const float* fp2_b1  = (const float*)d_in[15];
    const float* knn1_w0 = (const float*)d_in[16];
    const float* knn1_b0 = (const float*)d_in[17];
    const float* knn1_w1 = (const float*)d_in[18];
    const float* knn1_b1 = (const float*)d_in[19];
    const float* knn2_w0 = (const float*)d_in[20];
    const float* knn2_b0 = (const float*)d_in[21];
    const float* knn2_w1 = (const float*)d_in[22];
    const float* knn2_b1 = (const float*)d_in[23];
    const float* fin_w0  = (const float*)d_in[24];
    const float* fin_b0  = (const float*)d_in[25];
    const float* fin_w1  = (const float*)d_in[26];
    const float* fin_b1  = (const float*)d_in[27];
    float* out = (float*)d_out;

    // ---- workspace carve (floats); layout unchanged from R8 ----
    float* wsf    = (float*)d_ws;
    int*   minidx = (int*)wsf;                   // 131072 ints
    float* counts = wsf + 131072;                // 2048
    float* sums   = counts + 2048;               // 6144
    float* m1     = sums + 6144;                 // 65536
    int*   knnidx = (int*)(m1 + 65536);          // 8192 ints
    float* Xk     = (float*)(knnidx + 8192);     // 67*8192   = 548864
    float* Yk1    = Xk + 548864;                 // 256*8192  = 2097152
    float* Yk2    = Yk1 + 2097152;               // 256*8192  = 2097152
    float* pooled = Yk2 + 2097152;               // 256*512   = 131072
    float* Ppart  = pooled + 131072;             // 512*512   = 262144 (in old Zin slot)
    float* Z1     = Ppart + 4194304;             // 512*8192  = 4194304 (same addr as before)
    // aliases (lifetime-disjoint, verified in dependency order):
    float* Z2   = Yk1;          // Yk1 dead after knn1_w1 gemm
    float* FinX = Xk;           // Xk dead after Yk1 gemm
    float* F1   = Xk + 132608;  // fits: 132608+262144 <= 548864
    float* F2   = Ppart + 262144; // spare Zin-slot space, disjoint from Ppart & Z1

    // zero-init atomic targets (ws/out are poisoned 0xAA before every call)
    hipMemsetAsync(counts, 0, (2048 + 6144) * sizeof(float), stream);

    k_top3<<<dim3(64, 8), 256, 0, stream>>>(pc, node_a, out + OFF_MKI, minidx, counts, sums);
    k_mean<<<8, 256, 0, stream>>>(counts, sums, out + OFF_CM);
    k_fp1<<<dim3(64, 8), 256, 0, stream>>>(pc, inten, sn, label, minidx, out + OFF_CM,
                                           fp1_w0, fp1_b0, fp1_w1, fp1_b1, fp1_w2, fp1_b2,
                                           out + OFF_PCC, out + OFF_F1);
    k_segmax<<<8 * 32, 256, 0, stream>>>(out + OFF_F1, minidx, m1, 32);
    k_fp2<<<dim3(64, 8), 256, 0, stream>>>(out + OFF_F1, m1, minidx,
                                           fp2_w0, fp2_b0, fp2_w1, fp2_b1,
                                           out + OFF_F2);
    k_segmax<<<8 * 64, 256, 0, stream>>>(out + OFF_F2, minidx, out + OFF_NAF, 64);
    k_knn16<<<512, 64, 0, stream>>>(out + OFF_CM, node_b, knnidx);
    k_buildx<<<32, 256, 0, stream>>>(knnidx, out + OFF_CM, node_b, out + OFF_NAF, Xk);
    // knn1: y = relu(W0 @ X), relu(W1 @ y)
    gemm_relu<<<dim3(128, 4), 256, 0, stream>>>(knn1_w0, knn1_b0, Xk, Yk1,
                                                256, 67, 67, 8192, nullptr, 1);
    gemm_relu<<<dim3(128, 4), 256, 0, stream>>>(knn1_w1, knn1_b1, Yk1, Yk2,
                                                256, 256, 256, 8192, nullptr, 1);
    k_pool<<<512, 256, 0, stream>>>(Yk2, pooled);
    // knn2 layer 0, split: Ppart = W0[:, :256] @ pooled  (no bias/relu),
    // then Z1 = relu(W0[:, 256:] @ Yk2 + Ppart[o, c>>4] + b0)
    gemm_relu<<<dim3(8, 8), 256, 0, stream>>>(knn2_w0, nullptr, pooled, Ppart,
                                              512, 256, 512, 512, nullptr, 0);
    gemm_relu<<<dim3(128, 8), 256, 0, stream>>>(knn2_w0 + 256, knn2_b0, Yk2, Z1,
                                                512, 256, 512, 8192, Ppart, 1);
    gemm_relu<<<dim3(128, 4), 256, 0, stream>>>(knn2_w1, knn2_b1, Z1, Z2,
                                                256, 512, 512, 8192, nullptr, 1);
    k_maxk<<<512, 256, 0, stream>>>(Z2, out + OFF_NBF);
    k_finx<<<518, 256, 0, stream>>>(node_b, out + OFF_NBF, FinX);
    gemm_relu<<<dim3(8, 8), 256, 0, stream>>>(fin_w0, fin_b0, FinX, F1,
                                              512, 259, 259, 512, nullptr, 1);
    gemm_relu<<<dim3(8, 16), 256, 0, stream>>>(fin_w1, fin_b1, F1, F2,
                                               1024, 512, 512, 512, nullptr, 1);
    k_gmax<<<32, 256, 0, stream>>>(F2, out + OFF_GF);
}

// Round 14
// 611.695 us; speedup vs baseline: 1.1425x; 1.1425x over previous
//
#include <hip/hip_runtime.h>
#include <cstdint>
#include <cstddef>

#define B_   8
#define N_   16384
#define MA_  256
#define MB_  64
#define KI_  3
#define KAB_ 16

// output region offsets (floats)
#define OFF_PCC 0            // pc_centers      (8,3,16384)  393216
#define OFF_CM  393216       // cluster_mean    (8,3,256)    6144
#define OFF_MKI 399360       // min_k_idx       (8,16384,3)  393216 (as float)
#define OFF_F1  792576       // f1              (8,32,16384) 4194304
#define OFF_F2  4986880      // f2              (8,64,16384) 8388608
#define OFF_NAF 13375488     // node_a_features (8,64,256)   131072
#define OFF_NBF 13506560     // node_b_features (8,256,64)   131072
#define OFF_GF  13637632     // global_feature  (8,1024,1)   8192

// ---------------------------------------------------------------------------
// K1: per-point top-3 nearest node_a + fused segment count/sum atomics
// ---------------------------------------------------------------------------
__global__ __launch_bounds__(256) void k_top3(
    const float* __restrict__ pc, const float* __restrict__ node_a,
    float* __restrict__ out_mki, int* __restrict__ minidx,
    float* __restrict__ counts, float* __restrict__ sums)
{
#pragma clang fp contract(off)
    __shared__ float nax[MA_], nay[MA_], naz[MA_];
    int b = blockIdx.y;
    const float* na = node_a + (size_t)b * 3 * MA_;
    for (int t = threadIdx.x; t < MA_; t += 256) {
        nax[t] = na[t]; nay[t] = na[MA_ + t]; naz[t] = na[2 * MA_ + t];
    }
    __syncthreads();
    int n = blockIdx.x * 256 + threadIdx.x;
    const float* pcb = pc + (size_t)b * 3 * N_;
    float px = pcb[n], py = pcb[N_ + n], pz = pcb[2 * N_ + n];
    float d0 = 3.4e38f, d1 = 3.4e38f, d2 = 3.4e38f;
    int   i0 = 0, i1 = 0, i2 = 0;
    for (int m = 0; m < MA_; ++m) {
        float dx = px - nax[m];
        float dy = py - nay[m];
        float dz = pz - naz[m];
        float s = dx * dx;
        s = s + dy * dy;
        s = s + dz * dz;
        float d = sqrtf(s);
        // strict < keeps lower index first on ties (matches jax.lax.top_k)
        if (d < d2) {
            if (d < d1) {
                if (d < d0) { d2 = d1; i2 = i1; d1 = d0; i1 = i0; d0 = d; i0 = m; }
                else        { d2 = d1; i2 = i1; d1 = d;  i1 = m; }
            } else          { d2 = d;  i2 = m; }
        }
    }
    size_t base = ((size_t)b * N_ + n) * 3;
    out_mki[base + 0] = (float)i0;
    out_mki[base + 1] = (float)i1;
    out_mki[base + 2] = (float)i2;
    minidx[b * N_ + n] = i0;
    atomicAdd(&counts[b * MA_ + i0], 1.0f);
    atomicAdd(&sums[(b * 3 + 0) * MA_ + i0], px);
    atomicAdd(&sums[(b * 3 + 1) * MA_ + i0], py);
    atomicAdd(&sums[(b * 3 + 2) * MA_ + i0], pz);
}

// ---------------------------------------------------------------------------
// K2: cluster_mean = sums / (counts + 1e-5)
// ---------------------------------------------------------------------------
__global__ void k_mean(const float* __restrict__ counts, const float* __restrict__ sums,
                       float* __restrict__ out_cm)
{
    int tid = blockIdx.x * 256 + threadIdx.x;     // 2048
    int b = tid >> 8, m = tid & 255;
    float den = counts[tid] + 1e-5f;
    #pragma unroll
    for (int c = 0; c < 3; ++c)
        out_cm[(b * 3 + c) * MA_ + m] = sums[(b * 3 + c) * MA_ + m] / den;
}

// ---------------------------------------------------------------------------
// K3: per-point fp1 MLP (8->32->32->32), writes pc_centers & f1 (no atomics)
// ---------------------------------------------------------------------------
__global__ __launch_bounds__(256) void k_fp1(
    const float* __restrict__ pc, const float* __restrict__ inten,
    const float* __restrict__ sn, const float* __restrict__ label,
    const int* __restrict__ minidx, const float* __restrict__ cm,
    const float* __restrict__ w0, const float* __restrict__ b0,
    const float* __restrict__ w1, const float* __restrict__ b1,
    const float* __restrict__ w2, const float* __restrict__ b2,
    float* __restrict__ out_pcc, float* __restrict__ f1out)
{
    __shared__ float w0s[32 * 8], w1s[32 * 32], w2s[32 * 32];
    __shared__ float b0s[32], b1s[32], b2s[32];
    for (int t = threadIdx.x; t < 256; t += 256) w0s[t] = w0[t];
    for (int t = threadIdx.x; t < 1024; t += 256) { w1s[t] = w1[t]; w2s[t] = w2[t]; }
    if (threadIdx.x < 32) {
        b0s[threadIdx.x] = b0[threadIdx.x];
        b1s[threadIdx.x] = b1[threadIdx.x];
        b2s[threadIdx.x] = b2[threadIdx.x];
    }
    __syncthreads();
    int b = blockIdx.y;
    int n = blockIdx.x * 256 + threadIdx.x;
    int mi = minidx[b * N_ + n];
    float cx = cm[(b * 3 + 0) * MA_ + mi];
    float cy = cm[(b * 3 + 1) * MA_ + mi];
    float cz = cm[(b * 3 + 2) * MA_ + mi];
    const float* pcb = pc + (size_t)b * 3 * N_;
    const float* snb = sn + (size_t)b * 3 * N_;
    float x[8];
    x[0] = pcb[n] - cx; x[1] = pcb[N_ + n] - cy; x[2] = pcb[2 * N_ + n] - cz;
    x[3] = inten[(size_t)b * N_ + n];
    x[4] = snb[n]; x[5] = snb[N_ + n]; x[6] = snb[2 * N_ + n];
    x[7] = label[(size_t)b * N_ + n];
    out_pcc[(size_t)(b * 3 + 0) * N_ + n] = cx;
    out_pcc[(size_t)(b * 3 + 1) * N_ + n] = cy;
    out_pcc[(size_t)(b * 3 + 2) * N_ + n] = cz;

    float h1[32];
    #pragma unroll
    for (int o = 0; o < 32; ++o) {
        float a = b0s[o];
        #pragma unroll
        for (int i = 0; i < 8; ++i) a = fmaf(w0s[o * 8 + i], x[i], a);
        h1[o] = a > 0.f ? a : 0.f;
    }
    float h2[32];
    #pragma unroll
    for (int o = 0; o < 32; ++o) {
        float a = b1s[o];
        #pragma unroll
        for (int i = 0; i < 32; ++i) a = fmaf(w1s[o * 32 + i], h1[i], a);
        h2[o] = a > 0.f ? a : 0.f;
    }
    #pragma unroll
    for (int o = 0; o < 32; ++o) {
        float a = b2s[o];
        #pragma unroll
        for (int i = 0; i < 32; ++i) a = fmaf(w2s[o * 32 + i], h2[i], a);
        a = a > 0.f ? a : 0.f;
        f1out[(size_t)(b * 32 + o) * N_ + n] = a;
    }
}

// ---------------------------------------------------------------------------
// K3b: segment-max via LDS table. One block per (b, feature).
// values are post-ReLU (>=0) so float-as-int atomicMax is order-preserving;
// init 0 matches where(nonempty, seg_max, 0).
// ---------------------------------------------------------------------------
__global__ __launch_bounds__(256) void k_segmax(
    const float* __restrict__ f, const int* __restrict__ minidx,
    float* __restrict__ outt, int F)
{
    __shared__ int table[MA_];
    int blk = blockIdx.x;            // b*F + o
    int b = blk / F;
    table[threadIdx.x] = 0;
    __syncthreads();
    const float* frow = f + (size_t)blk * N_;
    const int*   mrow = minidx + (size_t)b * N_;
    #pragma unroll 4
    for (int it = 0; it < N_ / 256; ++it) {
        int n = it * 256 + threadIdx.x;
        float v = frow[n];
        int  mi = mrow[n];
        atomicMax(&table[mi], __float_as_int(v));
    }
    __syncthreads();
    outt[(size_t)blk * MA_ + threadIdx.x] = __int_as_float(table[threadIdx.x]);
}

// ---------------------------------------------------------------------------
// K4: per-point fp2 MLP (64->64->64), writes f2 (no atomics)
// ---------------------------------------------------------------------------
__global__ __launch_bounds__(256) void k_fp2(
    const float* __restrict__ f1, const float* __restrict__ m1,
    const int* __restrict__ minidx,
    const float* __restrict__ w0, const float* __restrict__ b0,
    const float* __restrict__ w1, const float* __restrict__ b1,
    float* __restrict__ f2out)
{
    __shared__ float w0t[64 * 65];   // transposed+padded: w0t[i*65+o] (pad kills staging bank conflicts)
    __shared__ float w1s[64 * 64];   // row-major:  w1s[o*64+i]
    __shared__ float b0s[64], b1s[64];
    for (int t = threadIdx.x; t < 4096; t += 256) {
        w0t[(t & 63) * 65 + (t >> 6)] = w0[t];
        w1s[t] = w1[t];
    }
    if (threadIdx.x < 64) {
        b0s[threadIdx.x] = b0[threadIdx.x];
        b1s[threadIdx.x] = b1[threadIdx.x];
    }
    __syncthreads();
    int b = blockIdx.y;
    int n = blockIdx.x * 256 + threadIdx.x;
    int mi = minidx[b * N_ + n];

    float h[64];
    #pragma unroll
    for (int o = 0; o < 64; ++o) h[o] = b0s[o];
    for (int i = 0; i < 32; ++i) {
        float xi = f1[(size_t)(b * 32 + i) * N_ + n];
        #pragma unroll
        for (int o = 0; o < 64; ++o) h[o] = fmaf(w0t[i * 65 + o], xi, h[o]);
    }
    for (int i = 0; i < 32; ++i) {
        float xi = m1[(b * 32 + i) * MA_ + mi];
        #pragma unroll
        for (int o = 0; o < 64; ++o) h[o] = fmaf(w0t[(32 + i) * 65 + o], xi, h[o]);
    }
    #pragma unroll
    for (int o = 0; o < 64; ++o) h[o] = h[o] > 0.f ? h[o] : 0.f;

    for (int o2 = 0; o2 < 64; ++o2) {
        float acc = b1s[o2];
        #pragma unroll
        for (int i = 0; i < 64; ++i) acc = fmaf(w1s[o2 * 64 + i], h[i], acc);
        acc = acc > 0.f ? acc : 0.f;
        f2out[(size_t)(b * 64 + o2) * N_ + n] = acc;
    }
}

// ---------------------------------------------------------------------------
// K5: per node_b: top-16 nearest cluster means.
// Wave-parallel selection: 16 rounds of 64-lane butterfly argmin with
// lower-index tie-break (matches jax.lax.top_k stability). Replaces the
// serial thread-0 scan (4096 dependent LDS iterations, ~85 us of the old
// 98 us dispatch).
// ---------------------------------------------------------------------------
__global__ __launch_bounds__(64) void k_knn16(
    const float* __restrict__ cm, const float* __restrict__ nb,
    int* __restrict__ knnidx)
{
#pragma clang fp contract(off)
    __shared__ float dist[MA_];
    int blk = blockIdx.x;            // b*64+mb
    int b = blk >> 6, mb = blk & 63;
    int t = threadIdx.x;
    float nbx = nb[(b * 3 + 0) * MB_ + mb];
    float nby = nb[(b * 3 + 1) * MB_ + mb];
    float nbz = nb[(b * 3 + 2) * MB_ + mb];
    for (int m = t; m < MA_; m += 64) {
        float dx = nbx - cm[(b * 3 + 0) * MA_ + m];
        float dy = nby - cm[(b * 3 + 1) * MA_ + m];
        float dz = nbz - cm[(b * 3 + 2) * MA_ + m];
        float s = dx * dx;
        s = s + dy * dy;
        s = s + dz * dz;
        dist[m] = sqrtf(s);
    }
    __syncthreads();
    for (int k = 0; k < KAB_; ++k) {
        // per-lane min over 4 strided entries (increasing m, strict < keeps lowest idx)
        float bv = 3.4e38f; int bi = MA_;
        #pragma unroll
        for (int j = 0; j < 4; ++j) {
            int m = t + j * 64;
            float d = dist[m];
            if (d < bv) { bv = d; bi = m; }
        }
        // 64-lane butterfly reduce; tie-break: lower index wins
        #pragma unroll
        for (int off = 32; off >= 1; off >>= 1) {
            float ov = __shfl_xor(bv, off, 64);
            int   oi = __shfl_xor(bi, off, 64);
            if (ov < bv || (ov == bv && oi < bi)) { bv = ov; bi = oi; }
        }
        if (t == 0) {
            knnidx[blk * KAB_ + k] = bi;
            dist[bi] = 3.4e38f;      // remove winner for next round
        }
        __syncthreads();
    }
}

// ---------------------------------------------------------------------------
// K6: build knn1 input matrix X (67 x 8192)
// ---------------------------------------------------------------------------
__global__ void k_buildx(const int* __restrict__ knnidx, const float* __restrict__ cm,
                         const float* __restrict__ nb, const float* __restrict__ naf,
                         float* __restrict__ Xk)
{
    int col = blockIdx.x * 256 + threadIdx.x;   // 8192
    int b = col >> 10;
    int mb = (col >> 4) & 63;
    int idx = knnidx[col];
    #pragma unroll
    for (int c = 0; c < 3; ++c)
        Xk[(size_t)c * 8192 + col] = cm[(b * 3 + c) * MA_ + idx] - nb[(b * 3 + c) * MB_ + mb];
    for (int f = 0; f < 64; ++f)
        Xk[(size_t)(3 + f) * 8192 + col] = naf[(b * 64 + f) * MA_ + idx];
}

// ---------------------------------------------------------------------------
// Tiled f32 GEMM + bias + optional relu + optional per-16-col-group add:
//   Y(O,C) = act( W(O,:)[:,0:I] @ X(I,C) + bias + gadd[o, c>>4] )
// W row stride = lda. 64x64 tile, BK=16, 256 threads, 4x4 per thread.
// Ws padded to 68 floats/row: staging-write bank = (16(t&3)+4j+(t>>2))%32
// covers all 32 banks 2-way (free) instead of 4-way on bank=(t>>2).
// ---------------------------------------------------------------------------
__global__ __launch_bounds__(256) void gemm_relu(
    const float* __restrict__ W, const float* __restrict__ bias,
    const float* __restrict__ X, float* __restrict__ Y,
    int O, int I, int lda, int C,
    const float* __restrict__ gadd, int do_relu)
{
    __shared__ float Ws[16][68];
    __shared__ float Xs[16][64];
    int t  = threadIdx.x;
    int tx = t & 15, ty = t >> 4;
    int obase = blockIdx.y * 64;
    int cbase = blockIdx.x * 64;
    float acc[4][4] = {};
    for (int k0 = 0; k0 < I; k0 += 16) {
        {   // load W tile (transposed into Ws[k][m])
            int m = t >> 2, kq = (t & 3) * 4;
            const float* wrow = W + (size_t)(obase + m) * lda + k0 + kq;
            #pragma unroll
            for (int j = 0; j < 4; ++j) {
                int kk = kq + j;
                Ws[kk][m] = (k0 + kk < I) ? wrow[j] : 0.f;
            }
            // load X tile (lane byte addr = 16*t: contiguous, conflict-free)
            int kx = t >> 4, nq = (t & 15) * 4;
            const float* xrow = X + (size_t)(k0 + kx) * C + cbase + nq;
            bool kok = (k0 + kx) < I;
            #pragma unroll
            for (int j = 0; j < 4; ++j)
                Xs[kx][nq + j] = kok ? xrow[j] : 0.f;
        }
        __syncthreads();
        #pragma unroll
        for (int kk = 0; kk < 16; ++kk) {
            float4 av = *(const float4*)&Ws[kk][ty * 4];
            float4 bv = *(const float4*)&Xs[kk][tx * 4];
            float am[4] = {av.x, av.y, av.z, av.w};
            float bn[4] = {bv.x, bv.y, bv.z, bv.w};
            #pragma unroll
            for (int i = 0; i < 4; ++i)
                #pragma unroll
                for (int j = 0; j < 4; ++j)
                    acc[i][j] = fmaf(am[i], bn[j], acc[i][j]);
        }
        __syncthreads();
    }
    #pragma unroll
    for (int i = 0; i < 4; ++i) {
        int o = obase + ty * 4 + i;
        float bb = bias ? bias[o] : 0.f;
        #pragma unroll
        for (int j = 0; j < 4; ++j) {
            int c = cbase + tx * 4 + j;
            float v = acc[i][j] + bb;
            if (gadd) v += gadd[(size_t)o * 512 + (c >> 4)];
            if (do_relu) v = v > 0.f ? v : 0.f;
            Y[(size_t)o * C + c] = v;
        }
    }
}

// ---------------------------------------------------------------------------
// K7: pooled(256,512) = max over k of Yk2
// ---------------------------------------------------------------------------
__global__ void k_pool(const float* __restrict__ Yk2, float* __restrict__ pooled)
{
    int tid = blockIdx.x * 256 + threadIdx.x;  // 131072
    int r = tid >> 9, g = tid & 511;
    const float* p = Yk2 + (size_t)r * 8192 + g * 16;
    float m = p[0];
    #pragma unroll
    for (int k = 1; k < 16; ++k) m = fmaxf(m, p[k]);
    pooled[r * 512 + g] = m;
}

// ---------------------------------------------------------------------------
// K9: node_b_features = max over k of Z2
// ---------------------------------------------------------------------------
__global__ void k_maxk(const float* __restrict__ Z2, float* __restrict__ nbf)
{
    int tid = blockIdx.x * 256 + threadIdx.x;  // 131072 = (b*256+o)*64+mb
    int mb = tid & 63;
    int o  = (tid >> 6) & 255;
    int b  = tid >> 14;
    const float* p = Z2 + (size_t)o * 8192 + (size_t)((b * 64 + mb) << 4);
    float m = p[0];
    #pragma unroll
    for (int k = 1; k < 16; ++k) m = fmaxf(m, p[k]);
    nbf[tid] = m;
}

// ---------------------------------------------------------------------------
// K10: build fin input (259 x 512)
// ---------------------------------------------------------------------------
__global__ void k_finx(const float* __restrict__ nb, const float* __restrict__ nbf,
                       float* __restrict__ FinX)
{
    int tid = blockIdx.x * 256 + threadIdx.x;  // 132608 = r*512+col
    if (tid >= 259 * 512) return;
    int col = tid & 511, r = tid >> 9;
    int b = col >> 6, mb = col & 63;
    float v = (r < 3) ? nb[(b * 3 + r) * MB_ + mb]
                      : nbf[(b * 256 + (r - 3)) * MB_ + mb];
    FinX[tid] = v;
}

// ---------------------------------------------------------------------------
// K11: global max over the 64 node_b columns
// ---------------------------------------------------------------------------
__global__ void k_gmax(const float* __restrict__ F2, float* __restrict__ gf)
{
    int tid = blockIdx.x * 256 + threadIdx.x;  // 8192 = b*1024+o
    int b = tid >> 10, o = tid & 1023;
    const float* p = F2 + (size_t)o * 512 + b * 64;
    float m = p[0];
    #pragma unroll
    for (int k = 1; k < 64; ++k) m = fmaxf(m, p[k]);
    gf[tid] = m;
}

// ---------------------------------------------------------------------------
extern "C" void kernel_launch(void* const* d_in, const int* in_sizes, int n_in,
                              void* d_out, int out_size, void* d_ws, size_t ws_size,
                              hipStream_t stream)
{
    (void)in_sizes; (void)n_in; (void)out_size; (void)ws_size;
    const float* pc      = (const float*)d_in[0];
    const float* inten   = (const float*)d_in[1];
    const float* sn      = (const float*)d_in[2];
    const float* label   = (const float*)d_in[3];
    const float* node_a  = (const float*)d_in[4];
    const float* node_b  = (const float*)d_in[5];
    const float* fp1_w0  = (const float*)d_in[6];
    const float* fp1_b0  = (const float*)d_in[7];
    const float* fp1_w1  = (const float*)d_in[8];
    const float* fp1_b1  = (const float*)d_in[9];
    const float* fp1_w2  = (const float*)d_in[10];
    const float* fp1_b2  = (const float*)d_in[11];
    const float* fp2_w0  = (const float*)d_in[12];
    const float* fp2_b0  = (const float*)d_in[13];
    const float* fp2_w1  = (const float*)d_in[14];
    const float* fp2_b1  = (const float*)d_in[15];
    const float* knn1_w0 = (const float*)d_in[16];
    const float* knn1_b0 = (const float*)d_in[17];
    const float* knn1_w1 = (const float*)d_in[18];
    const float* knn1_b1 = (const float*)d_in[19];
    const float* knn2_w0 = (const float*)d_in[20];
    const float* knn2_b0 = (const float*)d_in[21];
    const float* knn2_w1 = (const float*)d_in[22];
    const float* knn2_b1 = (const float*)d_in[23];
    const float* fin_w0  = (const float*)d_in[24];
    const float* fin_b0  = (const float*)d_in[25];
    const float* fin_w1  = (const float*)d_in[26];
    const float* fin_b1  = (const float*)d_in[27];
    float* out = (float*)d_out;

    // ---- workspace carve (floats) ----
    float* wsf    = (float*)d_ws;
    int*   minidx = (int*)wsf;                   // 131072 ints
    float* counts = wsf + 131072;                // 2048
    float* sums   = counts + 2048;               // 6144
    float* m1     = sums + 6144;                 // 65536
    int*   knnidx = (int*)(m1 + 65536);          // 8192 ints
    float* Xk     = (float*)(knnidx + 8192);     // 67*8192   = 548864
    float* Yk1    = Xk + 548864;                 // 256*8192  = 2097152
    float* Yk2    = Yk1 + 2097152;               // 256*8192  = 2097152
    float* pooled = Yk2 + 2097152;               // 256*512   = 131072
    float* Ppart  = pooled + 131072;             // 512*512   = 262144 (in old Zin slot)
    float* Z1     = Ppart + 4194304;             // 512*8192  = 4194304
    // aliases (lifetime-disjoint, verified in dependency order):
    float* Z2   = Yk1;          // Yk1 dead after knn1_w1 gemm
    float* FinX = Xk;           // Xk dead after Yk1 gemm
    float* F1   = Xk + 132608;  // fits: 132608+262144 <= 548864
    float* F2   = Ppart + 262144; // spare Zin-slot space, disjoint from Ppart & Z1

    // zero-init atomic targets (ws/out are poisoned 0xAA before every call)
    hipMemsetAsync(counts, 0, (2048 + 6144) * sizeof(float), stream);

    k_top3<<<dim3(64, 8), 256, 0, stream>>>(pc, node_a, out + OFF_MKI, minidx, counts, sums);
    k_mean<<<8, 256, 0, stream>>>(counts, sums, out + OFF_CM);
    k_fp1<<<dim3(64, 8), 256, 0, stream>>>(pc, inten, sn, label, minidx, out + OFF_CM,
                                           fp1_w0, fp1_b0, fp1_w1, fp1_b1, fp1_w2, fp1_b2,
                                           out + OFF_PCC, out + OFF_F1);
    k_segmax<<<8 * 32, 256, 0, stream>>>(out + OFF_F1, minidx, m1, 32);
    k_fp2<<<dim3(64, 8), 256, 0, stream>>>(out + OFF_F1, m1, minidx,
                                           fp2_w0, fp2_b0, fp2_w1, fp2_b1,
                                           out + OFF_F2);
    k_segmax<<<8 * 64, 256, 0, stream>>>(out + OFF_F2, minidx, out + OFF_NAF, 64);
    k_knn16<<<512, 64, 0, stream>>>(out + OFF_CM, node_b, knnidx);
    k_buildx<<<32, 256, 0, stream>>>(knnidx, out + OFF_CM, node_b, out + OFF_NAF, Xk);
    // knn1: y = relu(W0 @ X), relu(W1 @ y)
    gemm_relu<<<dim3(128, 4), 256, 0, stream>>>(knn1_w0, knn1_b0, Xk, Yk1,
                                                256, 67, 67, 8192, nullptr, 1);
    gemm_relu<<<dim3(128, 4), 256, 0, stream>>>(knn1_w1, knn1_b1, Yk1, Yk2,
                                                256, 256, 256, 8192, nullptr, 1);
    k_pool<<<512, 256, 0, stream>>>(Yk2, pooled);
    // knn2 layer 0, split: Ppart = W0[:, :256] @ pooled  (no bias/relu),
    // then Z1 = relu(W0[:, 256:] @ Yk2 + Ppart[o, c>>4] + b0)
    gemm_relu<<<dim3(8, 8), 256, 0, stream>>>(knn2_w0, nullptr, pooled, Ppart,
                                              512, 256, 512, 512, nullptr, 0);
    gemm_relu<<<dim3(128, 8), 256, 0, stream>>>(knn2_w0 + 256, knn2_b0, Yk2, Z1,
                                                512, 256, 512, 8192, Ppart, 1);
    gemm_relu<<<dim3(128, 4), 256, 0, stream>>>(knn2_w1, knn2_b1, Z1, Z2,
                                                256, 512, 512, 8192, nullptr, 1);
    k_maxk<<<512, 256, 0, stream>>>(Z2, out + OFF_NBF);
    k_finx<<<518, 256, 0, stream>>>(node_b, out + OFF_NBF, FinX);
    gemm_relu<<<dim3(8, 8), 256, 0, stream>>>(fin_w0, fin_b0, FinX, F1,
                                              512, 259, 259, 512, nullptr, 1);
    gemm_relu<<<dim3(8, 16), 256, 0, stream>>>(fin_w1, fin_b1, F1, F2,
                                               1024, 512, 512, 512, nullptr, 1);
    k_gmax<<<32, 256, 0, stream>>>(F2, out + OFF_GF);
}